// Round 2
// baseline (178.607 us; speedup 1.0000x reference)
//
#include <hip/hip_runtime.h>
#include <math.h>

#define IN_DIM 1024
#define OUT_DIM 1024
#define NROWS 8192
#define XSTRIDE 1025   // x rows: 1024 feats + 1 phase

typedef __attribute__((ext_vector_type(8))) short bf16x8;
typedef __attribute__((ext_vector_type(4))) float f32x4;

static __device__ __forceinline__ unsigned f2bf(float f) {
  union { float f; unsigned u; } v; v.f = f;
  unsigned u = v.u;
  return (u + 0x7fffu + ((u >> 16) & 1u)) >> 16;  // RTNE
}

// ---- prep: unchanged (measured ~8 us incl. overhead).
__global__ __launch_bounds__(256) void prep_kernel(
    const float* __restrict__ x, const float* __restrict__ W,
    unsigned short* __restrict__ Wb, unsigned short* __restrict__ F,
    float* __restrict__ coef)
{
  const int blk = blockIdx.x;
  if (blk < 2048) {
    const int t = blk * 256 + threadIdx.x;
    const int flat = t * 8;                    // 8 elems of W
    const int k = flat >> 20;
    const int o = (flat >> 10) & 1023;
    const int i = flat & 1023;                 // multiple of 8
    const float4 fa = *reinterpret_cast<const float4*>(W + flat);
    const float4 fb = *reinterpret_cast<const float4*>(W + flat + 4);
    uint4 pk;
    pk.x = f2bf(fa.x) | (f2bf(fa.y) << 16);
    pk.y = f2bf(fa.z) | (f2bf(fa.w) << 16);
    pk.z = f2bf(fb.x) | (f2bf(fb.y) << 16);
    pk.w = f2bf(fb.z) | (f2bf(fb.w) << 16);
    const int g = (o & 15) | (k << 4) | ((o >> 4) << 6);
    *reinterpret_cast<uint4*>(Wb + (size_t)g * 1024 + i) = pk;
  } else {
    const int b = blk - 2048;
    const float* xr = x + (size_t)b * XSTRIDE;
    const int i = threadIdx.x * 4;
    ushort4 vv;
    vv.x = (unsigned short)f2bf(xr[i]);     vv.y = (unsigned short)f2bf(xr[i + 1]);
    vv.z = (unsigned short)f2bf(xr[i + 2]); vv.w = (unsigned short)f2bf(xr[i + 3]);
    *reinterpret_cast<ushort4*>(F + (size_t)b * 1024 + i) = vv;
    if (threadIdx.x == 0) {
      const float ps = 4.0f * xr[IN_DIM];
      const int ip = (int)ps;            // trunc, ps in [0,4)
      const int i1 = ip & 3;
      const float mu = ps - (float)ip;
      const float mu2 = mu * mu, mu3 = mu2 * mu;
      const float c0 = -0.5f * mu3 +        mu2 - 0.5f * mu;
      const float c1 =  1.5f * mu3 - 2.5f * mu2 + 1.0f;
      const float c2 = -1.5f * mu3 + 2.0f * mu2 + 0.5f * mu;
      const float c3 =  0.5f * mu3 - 0.5f * mu2;
      const int d0 = (0-i1)&3, d1 = (1-i1)&3, d2 = (2-i1)&3, d3 = (3-i1)&3;
      float4 cv;
      cv.x = d0==0 ? c1 : d0==1 ? c2 : d0==2 ? c3 : c0;
      cv.y = d1==0 ? c1 : d1==1 ? c2 : d1==2 ? c3 : c0;
      cv.z = d2==0 ? c1 : d2==1 ? c2 : d2==2 ? c3 : c0;
      cv.w = d3==0 ? c1 : d3==1 ? c2 : d3==2 ? c3 : c0;
      *reinterpret_cast<float4*>(coef + (size_t)b * 4) = cv;
    }
  }
}

// ---- GEMM: 256x256 tile, 8 waves (2M x 4N), 8-phase schedule with
// READS-AHEAD-BY-ONE-PHASE: each phase issues the ds_reads feeding the NEXT
// phase's MFMA (double-buffered fragment regs), so the LDS unit processes them
// during the current MFMA issue window. No hand-written lgkm waits — the
// compiler emits counted lgkmcnt before each first use (never drains to 0).
// Counted vmcnt(2) only at P4/P8, placed BEFORE that phase's buf-read issue.
// Staging ledger (tile kt=2i -> buf0, kt+1 -> buf1):
//   buf1 tile kt+1 staged P8(i-1),P1,P2,P3(i); gated vmcnt(2)@P4(i)
//   buf0 tile kt+2 staged P4,P5,P6,P7(i);      gated vmcnt(2)@P8(i)
#define BM 256
#define BN 256
#define BK 64

__global__ __launch_bounds__(512, 2) void gemm_kernel(
    const unsigned short* __restrict__ F,    // 8192x1024 bf16
    const unsigned short* __restrict__ Wb,   // 4096x1024 bf16, g-layout
    const float* __restrict__ coef,          // 8192x4 f32
    const float* __restrict__ bias,          // 4x1024 f32
    float* __restrict__ out)
{
  __shared__ unsigned short As[2][BM * BK];   // 64 KB
  __shared__ unsigned short Bs[2][BN * BK];   // 64 KB  (128 KB total)

  const int tid  = threadIdx.x;
  const int wave = tid >> 6;
  const int lane = tid & 63;
  const int row0  = blockIdx.y * BM;
  const int col0g = blockIdx.x * BN;       // g-row base of Wall

  // staging: 512 threads x 16B = one 64-row slab; XOR chunk swizzle on global source
  const int srow = tid >> 3;               // 0..63
  const int scc  = tid & 7;
  const int sgc  = (scc ^ (srow & 7)) * 8;

  const int wr = (wave >> 2) * 128;        // 2 M-waves
  const int wc = (wave & 3) * 64;          // 4 N-waves
  const int fm = lane & 15;
  const int fq = lane >> 4;
  const int c0 = ((fq    ) ^ (fm & 7)) * 8;  // k-chunk for kk=0
  const int c1 = ((4 + fq) ^ (fm & 7)) * 8;  // k-chunk for kk=32

  f32x4 acc[8][4];   // [mi][ni=knot]; mi<4 = quad0 rows, mi>=4 = quad1
  const f32x4 zero = {0.f, 0.f, 0.f, 0.f};
  #pragma unroll
  for (int a = 0; a < 8; a++)
    #pragma unroll
    for (int b = 0; b < 4; b++)
      acc[a][b] = zero;

  const unsigned short* Abase = F  + (size_t)row0  * 1024;
  const unsigned short* Bbase = Wb + (size_t)col0g * 1024;

  // double-buffered fragment registers (all indices compile-time)
  bf16x8 A0[4][2], A1[4][2];     // A quad0 / quad1 of current buf
  bf16x8 B01a[2][2], B01b[2][2]; // B cols 0-1, alternating buf parity
  bf16x8 B23[2][2];              // B cols 2-3 (no lifetime overlap)

#define STAGE(GB, LDSARR, tile, half) do {                                     \
    _Pragma("unroll")                                                          \
    for (int j_ = 0; j_ < 2; ++j_) {                                           \
      const int r_ = ((half) << 7) + (j_ << 6) + srow;                         \
      __builtin_amdgcn_global_load_lds(                                        \
        (const __attribute__((address_space(1))) void*)(                       \
            (GB) + (size_t)r_ * 1024 + ((tile) << 6) + sgc),                   \
        (__attribute__((address_space(3))) void*)(                             \
            &LDSARR[(tile) & 1][r_ * BK + scc * 8]),                           \
        16, 0, 0);                                                             \
    } } while (0)

#define DS_A(DST, buf, q)                                                      \
    _Pragma("unroll")                                                          \
    for (int mi_ = 0; mi_ < 4; ++mi_) {                                        \
      const unsigned short* p_ = &As[buf][(wr + (q) * 64 + mi_ * 16 + fm) * BK]; \
      DST[mi_][0] = *reinterpret_cast<const bf16x8*>(p_ + c0);                 \
      DST[mi_][1] = *reinterpret_cast<const bf16x8*>(p_ + c1);                 \
    }

#define DS_B(DST, buf, n0)                                                     \
    _Pragma("unroll")                                                          \
    for (int ni_ = 0; ni_ < 2; ++ni_) {                                        \
      const unsigned short* p_ = &Bs[buf][(wc + ((n0) + ni_) * 16 + fm) * BK]; \
      DST[ni_][0] = *reinterpret_cast<const bf16x8*>(p_ + c0);                 \
      DST[ni_][1] = *reinterpret_cast<const bf16x8*>(p_ + c1);                 \
    }

#define MF(q, AR, BR, n0) do {                                                 \
    __builtin_amdgcn_s_setprio(1);                                             \
    _Pragma("unroll")                                                          \
    for (int mi_ = 0; mi_ < 4; ++mi_)                                          \
      _Pragma("unroll")                                                        \
      for (int ni_ = 0; ni_ < 2; ++ni_)                                        \
        _Pragma("unroll")                                                      \
        for (int s_ = 0; s_ < 2; ++s_)                                         \
          acc[(q) * 4 + mi_][(n0) + ni_] =                                     \
              __builtin_amdgcn_mfma_f32_16x16x32_bf16(                         \
                  AR[mi_][s_], BR[ni_][s_],                                    \
                  acc[(q) * 4 + mi_][(n0) + ni_], 0, 0, 0);                    \
    __builtin_amdgcn_s_setprio(0);                                             \
  } while (0)

#define BAR __builtin_amdgcn_s_barrier()
#define VMCNT(N) asm volatile("s_waitcnt vmcnt(" #N ")" ::: "memory")

  // ---- prologue: stage K-tiles 0 (buf0) and 1 (buf1); preload P1's fragments
  STAGE(Abase, As, 0, 0); STAGE(Abase, As, 0, 1);
  STAGE(Bbase, Bs, 0, 0); STAGE(Bbase, Bs, 0, 1);
  STAGE(Abase, As, 1, 0); STAGE(Abase, As, 1, 1);
  STAGE(Bbase, Bs, 1, 0); STAGE(Bbase, Bs, 1, 1);
  VMCNT(8);                      // tile0 landed; tile1 in flight
  DS_A(A0, 0, 0);                // Aq0(buf0)   -> for P1
  DS_B(B01a, 0, 0);              // B01 (buf0)  -> for P1
  BAR;

  #pragma unroll 1
  for (int i = 0; i < 8; ++i) {
    const int kt = 2 * i;
    // ---- P1: MFMA q0 x n01 (buf0). reads: B23(buf0) for P2.
    DS_B(B23, 0, 2);
    if (i >= 1) STAGE(Abase, As, kt + 1, 1);
    BAR;
    MF(0, A0, B01a, 0);
    BAR;
    // ---- P2: MFMA q0 x n23. reads: Aq1(buf0) for P3.
    DS_A(A1, 0, 1);
    if (i >= 1) STAGE(Bbase, Bs, kt + 1, 0);
    BAR;
    MF(0, A0, B23, 2);
    BAR;
    // ---- P3: MFMA q1 x n23. no reads (P4 reuses A1,B01a).
    if (i >= 1) STAGE(Bbase, Bs, kt + 1, 1);
    BAR;
    MF(1, A1, B23, 2);
    BAR;
    // ---- P4: gate buf1; reads: Aq0(buf1) for P5 (pre), B01(buf1) (post).
    if (i < 7) { STAGE(Abase, As, kt + 2, 0); VMCNT(2); }
    else        VMCNT(0);
    DS_A(A0, 1, 0);
    BAR;
    MF(1, A1, B01a, 0);
    DS_B(B01b, 1, 0);
    BAR;
    // ---- P5: MFMA q0 x n01 (buf1). reads: B23(buf1) for P6.
    DS_B(B23, 1, 2);
    if (i < 7) STAGE(Abase, As, kt + 2, 1);
    BAR;
    MF(0, A0, B01b, 0);
    BAR;
    // ---- P6: MFMA q0 x n23. reads: Aq1(buf1) for P7.
    DS_A(A1, 1, 1);
    if (i < 7) STAGE(Bbase, Bs, kt + 2, 0);
    BAR;
    MF(0, A0, B23, 2);
    BAR;
    // ---- P7: MFMA q1 x n23. no reads.
    if (i < 7) STAGE(Bbase, Bs, kt + 2, 1);
    BAR;
    MF(1, A1, B23, 2);
    BAR;
    // ---- P8: gate next buf0; reads: Aq0(tile kt+2) pre, B01(tile kt+2) post.
    if (i < 7) {
      STAGE(Abase, As, kt + 3, 0);
      VMCNT(2);
      DS_A(A0, 0, 0);
    }
    BAR;
    MF(1, A1, B01b, 0);
    if (i < 7) DS_B(B01a, 0, 0);
    BAR;
  }

  // ---- epilogue: v = sum_k c_k*(acc_k + bias_k[o]); fast elu; dense store
  const int o = fm + 16 * ((col0g + wc) >> 6);   // this lane's output column
  const float b0 = bias[o];
  const float b1 = bias[OUT_DIM + o];
  const float b2 = bias[2 * OUT_DIM + o];
  const float b3 = bias[3 * OUT_DIM + o];
  #pragma unroll
  for (int mi = 0; mi < 8; ++mi) {
    #pragma unroll
    for (int r = 0; r < 4; ++r) {
      const int rloc = wr + mi * 16 + (fq << 2) + r;
      const float4 c = *reinterpret_cast<const float4*>(coef + (size_t)(row0 + rloc) * 4);
      float v = c.x * (acc[mi][0][r] + b0)
              + c.y * (acc[mi][1][r] + b1)
              + c.z * (acc[mi][2][r] + b2)
              + c.w * (acc[mi][3][r] + b3);
      // elu(alpha=1): exp(v)-1 via hw v_exp_f32; abs err ~1e-7 << 4.3e-3 threshold
      const float e = __expf(v) - 1.0f;
      v = (v > 0.0f) ? v : e;
      out[(size_t)(row0 + rloc) * OUT_DIM + o] = v;
    }
  }
#undef STAGE
#undef DS_A
#undef DS_B
#undef MF
#undef BAR
#undef VMCNT
}

extern "C" void kernel_launch(void* const* d_in, const int* in_sizes, int n_in,
                              void* d_out, int out_size, void* d_ws, size_t ws_size,
                              hipStream_t stream) {
  const float* x  = (const float*)d_in[0];   // (8192, 1025)
  const float* wk = (const float*)d_in[1];   // (4, 1024, 1024)
  const float* bk = (const float*)d_in[2];   // (4, 1024)
  float* out = (float*)d_out;                // (8192, 1024) fp32

  char* ws = (char*)d_ws;
  unsigned short* Wb = (unsigned short*)ws;                   // 8 MB
  unsigned short* F  = (unsigned short*)(ws + (8u << 20));    // 16 MB
  float* coef        = (float*)(ws + (24u << 20));            // 128 KB

  hipLaunchKernelGGL(prep_kernel, dim3(2048 + NROWS), dim3(256), 0, stream,
                     x, wk, Wb, F, coef);
  hipLaunchKernelGGL(gemm_kernel, dim3(4096 / BN, NROWS / BM), dim3(512), 0, stream,
                     F, Wb, coef, bk, out);
}

// Round 3
// 161.303 us; speedup vs baseline: 1.1073x; 1.1073x over previous
//
#include <hip/hip_runtime.h>
#include <math.h>

#define IN_DIM 1024
#define OUT_DIM 1024
#define NROWS 8192
#define XSTRIDE 1025   // x rows: 1024 feats + 1 phase

typedef __attribute__((ext_vector_type(8))) short bf16x8;
typedef __attribute__((ext_vector_type(4))) float f32x4;

static __device__ __forceinline__ unsigned f2bf(float f) {
  union { float f; unsigned u; } v; v.f = f;
  unsigned u = v.u;
  return (u + 0x7fffu + ((u >> 16) & 1u)) >> 16;  // RTNE
}

// ---- prep: unchanged.
__global__ __launch_bounds__(256) void prep_kernel(
    const float* __restrict__ x, const float* __restrict__ W,
    unsigned short* __restrict__ Wb, unsigned short* __restrict__ F,
    float* __restrict__ coef)
{
  const int blk = blockIdx.x;
  if (blk < 2048) {
    const int t = blk * 256 + threadIdx.x;
    const int flat = t * 8;                    // 8 elems of W
    const int k = flat >> 20;
    const int o = (flat >> 10) & 1023;
    const int i = flat & 1023;                 // multiple of 8
    const float4 fa = *reinterpret_cast<const float4*>(W + flat);
    const float4 fb = *reinterpret_cast<const float4*>(W + flat + 4);
    uint4 pk;
    pk.x = f2bf(fa.x) | (f2bf(fa.y) << 16);
    pk.y = f2bf(fa.z) | (f2bf(fa.w) << 16);
    pk.z = f2bf(fb.x) | (f2bf(fb.y) << 16);
    pk.w = f2bf(fb.z) | (f2bf(fb.w) << 16);
    const int g = (o & 15) | (k << 4) | ((o >> 4) << 6);
    *reinterpret_cast<uint4*>(Wb + (size_t)g * 1024 + i) = pk;
  } else {
    const int b = blk - 2048;
    const float* xr = x + (size_t)b * XSTRIDE;
    const int i = threadIdx.x * 4;
    ushort4 vv;
    vv.x = (unsigned short)f2bf(xr[i]);     vv.y = (unsigned short)f2bf(xr[i + 1]);
    vv.z = (unsigned short)f2bf(xr[i + 2]); vv.w = (unsigned short)f2bf(xr[i + 3]);
    *reinterpret_cast<ushort4*>(F + (size_t)b * 1024 + i) = vv;
    if (threadIdx.x == 0) {
      const float ps = 4.0f * xr[IN_DIM];
      const int ip = (int)ps;            // trunc, ps in [0,4)
      const int i1 = ip & 3;
      const float mu = ps - (float)ip;
      const float mu2 = mu * mu, mu3 = mu2 * mu;
      const float c0 = -0.5f * mu3 +        mu2 - 0.5f * mu;
      const float c1 =  1.5f * mu3 - 2.5f * mu2 + 1.0f;
      const float c2 = -1.5f * mu3 + 2.0f * mu2 + 0.5f * mu;
      const float c3 =  0.5f * mu3 - 0.5f * mu2;
      const int d0 = (0-i1)&3, d1 = (1-i1)&3, d2 = (2-i1)&3, d3 = (3-i1)&3;
      float4 cv;
      cv.x = d0==0 ? c1 : d0==1 ? c2 : d0==2 ? c3 : c0;
      cv.y = d1==0 ? c1 : d1==1 ? c2 : d1==2 ? c3 : c0;
      cv.z = d2==0 ? c1 : d2==1 ? c2 : d2==2 ? c3 : c0;
      cv.w = d3==0 ? c1 : d3==1 ? c2 : d3==2 ? c3 : c0;
      *reinterpret_cast<float4*>(coef + (size_t)b * 4) = cv;
    }
  }
}

// ---- GEMM: 256x256 tile, 8 waves (2M x 4N), 8-phase counted-vmcnt schedule.
// Round-1 structure (register-lean: shared areg/breg, 240 regs total, no spill)
// with the sched_barrier(0) poison removed: bare lgkmcnt(0) after the barrier
// (m201 template) so the compiler is free to interleave ds_read issue, address
// math, and MFMA within and across phases.
// Staging ledger (tile kt=2i -> buf0, kt+1 -> buf1):
//   buf1 tile kt+1 staged P8(i-1),P1,P2,P3(i); gated vmcnt(2)@P4(i)
//   buf0 tile kt+2 staged P4,P5,P6,P7(i);      gated vmcnt(2)@P8(i)
#define BM 256
#define BN 256
#define BK 64

__global__ __launch_bounds__(512, 2) void gemm_kernel(
    const unsigned short* __restrict__ F,    // 8192x1024 bf16
    const unsigned short* __restrict__ Wb,   // 4096x1024 bf16, g-layout
    const float* __restrict__ coef,          // 8192x4 f32
    const float* __restrict__ bias,          // 4x1024 f32
    float* __restrict__ out)
{
  __shared__ unsigned short As[2][BM * BK];   // 64 KB
  __shared__ unsigned short Bs[2][BN * BK];   // 64 KB  (128 KB total)

  const int tid  = threadIdx.x;
  const int wave = tid >> 6;
  const int lane = tid & 63;
  const int row0  = blockIdx.y * BM;
  const int col0g = blockIdx.x * BN;       // g-row base of Wall

  // staging: 512 threads x 16B = one 64-row slab; XOR chunk swizzle on global source
  const int srow = tid >> 3;               // 0..63
  const int scc  = tid & 7;
  const int sgc  = (scc ^ (srow & 7)) * 8;

  const int wr = (wave >> 2) * 128;        // 2 M-waves
  const int wc = (wave & 3) * 64;          // 4 N-waves
  const int fm = lane & 15;
  const int fq = lane >> 4;
  const int c0 = ((fq    ) ^ (fm & 7)) * 8;  // k-chunk for kk=0
  const int c1 = ((4 + fq) ^ (fm & 7)) * 8;  // k-chunk for kk=32

  f32x4 acc[8][4];   // [mi][ni=knot]; mi<4 = quad0 rows, mi>=4 = quad1
  const f32x4 zero = {0.f, 0.f, 0.f, 0.f};
  #pragma unroll
  for (int a = 0; a < 8; a++)
    #pragma unroll
    for (int b = 0; b < 4; b++)
      acc[a][b] = zero;

  const unsigned short* Abase = F  + (size_t)row0  * 1024;
  const unsigned short* Bbase = Wb + (size_t)col0g * 1024;

  bf16x8 areg[4][2];   // current A quadrant (4 mi x 2 k-steps)
  bf16x8 breg[4][2];   // full B panel      (4 ni x 2 k-steps)

#define STAGE(GB, LDSARR, tile, half) do {                                     \
    _Pragma("unroll")                                                          \
    for (int j_ = 0; j_ < 2; ++j_) {                                           \
      const int r_ = ((half) << 7) + (j_ << 6) + srow;                         \
      __builtin_amdgcn_global_load_lds(                                        \
        (const __attribute__((address_space(1))) void*)(                       \
            (GB) + (size_t)r_ * 1024 + ((tile) << 6) + sgc),                   \
        (__attribute__((address_space(3))) void*)(                             \
            &LDSARR[(tile) & 1][r_ * BK + scc * 8]),                           \
        16, 0, 0);                                                             \
    } } while (0)

#define LDA_QUAD(buf, q)                                                       \
    _Pragma("unroll")                                                          \
    for (int mi_ = 0; mi_ < 4; ++mi_) {                                        \
      const unsigned short* p_ = &As[buf][(wr + (q) * 64 + mi_ * 16 + fm) * BK]; \
      areg[mi_][0] = *reinterpret_cast<const bf16x8*>(p_ + c0);                \
      areg[mi_][1] = *reinterpret_cast<const bf16x8*>(p_ + c1);                \
    }

#define LDB_PAIR(buf, n0)                                                      \
    _Pragma("unroll")                                                          \
    for (int ni_ = 0; ni_ < 2; ++ni_) {                                        \
      const unsigned short* p_ = &Bs[buf][(wc + ((n0) + ni_) * 16 + fm) * BK]; \
      breg[(n0) + ni_][0] = *reinterpret_cast<const bf16x8*>(p_ + c0);         \
      breg[(n0) + ni_][1] = *reinterpret_cast<const bf16x8*>(p_ + c1);         \
    }

#define MFMA_QUAD(q, n0) do {                                                  \
    __builtin_amdgcn_s_setprio(1);                                             \
    _Pragma("unroll")                                                          \
    for (int mi_ = 0; mi_ < 4; ++mi_)                                          \
      _Pragma("unroll")                                                        \
      for (int ni_ = 0; ni_ < 2; ++ni_)                                        \
        _Pragma("unroll")                                                      \
        for (int s_ = 0; s_ < 2; ++s_)                                         \
          acc[(q) * 4 + mi_][(n0) + ni_] =                                     \
              __builtin_amdgcn_mfma_f32_16x16x32_bf16(                         \
                  areg[mi_][s_], breg[(n0) + ni_][s_],                         \
                  acc[(q) * 4 + mi_][(n0) + ni_], 0, 0, 0);                    \
    __builtin_amdgcn_s_setprio(0);                                             \
  } while (0)

#define BAR __builtin_amdgcn_s_barrier()
#define LGKM0 asm volatile("s_waitcnt lgkmcnt(0)" ::: "memory")
#define VMCNT(N) asm volatile("s_waitcnt vmcnt(" #N ")" ::: "memory")

  // ---- prologue: stage K-tiles 0 (buf0) and 1 (buf1)
  STAGE(Abase, As, 0, 0); STAGE(Abase, As, 0, 1);
  STAGE(Bbase, Bs, 0, 0); STAGE(Bbase, Bs, 0, 1);
  STAGE(Abase, As, 1, 0); STAGE(Abase, As, 1, 1);
  STAGE(Bbase, Bs, 1, 0); STAGE(Bbase, Bs, 1, 1);
  VMCNT(8);                      // tile0 landed; tile1 in flight
  BAR;

  #pragma unroll 1
  for (int i = 0; i < 8; ++i) {
    const int kt = 2 * i;
    // ---- P1: A quad0 + B ni0-1 from buf0
    LDA_QUAD(0, 0);
    LDB_PAIR(0, 0);
    if (i >= 1) STAGE(Abase, As, kt + 1, 1);
    BAR; LGKM0; MFMA_QUAD(0, 0); BAR;
    // ---- P2: B ni2-3
    LDB_PAIR(0, 2);
    if (i >= 1) STAGE(Bbase, Bs, kt + 1, 0);
    BAR; LGKM0; MFMA_QUAD(0, 2); BAR;
    // ---- P3: A quad1 (buf0 fully consumed after this phase)
    LDA_QUAD(0, 1);
    if (i >= 1) STAGE(Bbase, Bs, kt + 1, 1);
    BAR; LGKM0; MFMA_QUAD(1, 2); BAR;
    // ---- P4: no ds reads; start refilling buf0; ensure buf1's tile landed
    if (i < 7) { STAGE(Abase, As, kt + 2, 0); VMCNT(2); }
    else        VMCNT(0);
    BAR; MFMA_QUAD(1, 0); BAR;
    // ---- P5: A quad0 + B ni0-1 from buf1
    LDA_QUAD(1, 0);
    LDB_PAIR(1, 0);
    if (i < 7) STAGE(Abase, As, kt + 2, 1);
    BAR; LGKM0; MFMA_QUAD(0, 0); BAR;
    // ---- P6
    LDB_PAIR(1, 2);
    if (i < 7) STAGE(Bbase, Bs, kt + 2, 0);
    BAR; LGKM0; MFMA_QUAD(0, 2); BAR;
    // ---- P7 (buf1 fully consumed after this phase)
    LDA_QUAD(1, 1);
    if (i < 7) STAGE(Bbase, Bs, kt + 2, 1);
    BAR; LGKM0; MFMA_QUAD(1, 2); BAR;
    // ---- P8: start refilling buf1; ensure buf0's next tile landed
    if (i < 7) { STAGE(Abase, As, kt + 3, 0); VMCNT(2); }
    BAR; MFMA_QUAD(1, 0); BAR;
  }

  // ---- epilogue: v = sum_k c_k*(acc_k + bias_k[o]); fast elu; dense store
  const int o = fm + 16 * ((col0g + wc) >> 6);   // this lane's output column
  const float b0 = bias[o];
  const float b1 = bias[OUT_DIM + o];
  const float b2 = bias[2 * OUT_DIM + o];
  const float b3 = bias[3 * OUT_DIM + o];
  #pragma unroll
  for (int mi = 0; mi < 8; ++mi) {
    #pragma unroll
    for (int r = 0; r < 4; ++r) {
      const int rloc = wr + mi * 16 + (fq << 2) + r;
      const float4 c = *reinterpret_cast<const float4*>(coef + (size_t)(row0 + rloc) * 4);
      float v = c.x * (acc[mi][0][r] + b0)
              + c.y * (acc[mi][1][r] + b1)
              + c.z * (acc[mi][2][r] + b2)
              + c.w * (acc[mi][3][r] + b3);
      // elu(alpha=1): exp(v)-1 via hw v_exp_f32; abs err ~1e-7 << 4.3e-3 threshold
      const float e = __expf(v) - 1.0f;
      v = (v > 0.0f) ? v : e;
      out[(size_t)(row0 + rloc) * OUT_DIM + o] = v;
    }
  }
#undef STAGE
#undef LDA_QUAD
#undef LDB_PAIR
#undef MFMA_QUAD
#undef BAR
#undef LGKM0
#undef VMCNT
}

extern "C" void kernel_launch(void* const* d_in, const int* in_sizes, int n_in,
                              void* d_out, int out_size, void* d_ws, size_t ws_size,
                              hipStream_t stream) {
  const float* x  = (const float*)d_in[0];   // (8192, 1025)
  const float* wk = (const float*)d_in[1];   // (4, 1024, 1024)
  const float* bk = (const float*)d_in[2];   // (4, 1024)
  float* out = (float*)d_out;                // (8192, 1024) fp32

  char* ws = (char*)d_ws;
  unsigned short* Wb = (unsigned short*)ws;                   // 8 MB
  unsigned short* F  = (unsigned short*)(ws + (8u << 20));    // 16 MB
  float* coef        = (float*)(ws + (24u << 20));            // 128 KB

  hipLaunchKernelGGL(prep_kernel, dim3(2048 + NROWS), dim3(256), 0, stream,
                     x, wk, Wb, F, coef);
  hipLaunchKernelGGL(gemm_kernel, dim3(4096 / BN, NROWS / BM), dim3(512), 0, stream,
                     F, Wb, coef, bk, out);
}

// Round 4
// 156.272 us; speedup vs baseline: 1.1429x; 1.0322x over previous
//
#include <hip/hip_runtime.h>
#include <math.h>

#define IN_DIM 1024
#define OUT_DIM 1024
#define NROWS 8192
#define XSTRIDE 1025   // x rows: 1024 feats + 1 phase

typedef __attribute__((ext_vector_type(8))) short bf16x8;
typedef __attribute__((ext_vector_type(4))) float f32x4;

static __device__ __forceinline__ unsigned f2bf(float f) {
  union { float f; unsigned u; } v; v.f = f;
  unsigned u = v.u;
  return (u + 0x7fffu + ((u >> 16) & 1u)) >> 16;  // RTNE
}

// ---- prep: unchanged.
//  blocks [0,2048):    W(4,1024,1024) f32 -> Wall bf16, row g=(o&15)|(k<<4)|((o>>4)<<6)
//  blocks [2048,10240): feats -> F bf16 (8192x1024); thread 0 also writes coef[b] (float4)
__global__ __launch_bounds__(256) void prep_kernel(
    const float* __restrict__ x, const float* __restrict__ W,
    unsigned short* __restrict__ Wb, unsigned short* __restrict__ F,
    float* __restrict__ coef)
{
  const int blk = blockIdx.x;
  if (blk < 2048) {
    const int t = blk * 256 + threadIdx.x;
    const int flat = t * 8;                    // 8 elems of W
    const int k = flat >> 20;
    const int o = (flat >> 10) & 1023;
    const int i = flat & 1023;                 // multiple of 8
    const float4 fa = *reinterpret_cast<const float4*>(W + flat);
    const float4 fb = *reinterpret_cast<const float4*>(W + flat + 4);
    uint4 pk;
    pk.x = f2bf(fa.x) | (f2bf(fa.y) << 16);
    pk.y = f2bf(fa.z) | (f2bf(fa.w) << 16);
    pk.z = f2bf(fb.x) | (f2bf(fb.y) << 16);
    pk.w = f2bf(fb.z) | (f2bf(fb.w) << 16);
    const int g = (o & 15) | (k << 4) | ((o >> 4) << 6);
    *reinterpret_cast<uint4*>(Wb + (size_t)g * 1024 + i) = pk;
  } else {
    const int b = blk - 2048;
    const float* xr = x + (size_t)b * XSTRIDE;
    const int i = threadIdx.x * 4;
    ushort4 vv;
    vv.x = (unsigned short)f2bf(xr[i]);     vv.y = (unsigned short)f2bf(xr[i + 1]);
    vv.z = (unsigned short)f2bf(xr[i + 2]); vv.w = (unsigned short)f2bf(xr[i + 3]);
    *reinterpret_cast<ushort4*>(F + (size_t)b * 1024 + i) = vv;
    if (threadIdx.x == 0) {
      const float ps = 4.0f * xr[IN_DIM];
      const int ip = (int)ps;            // trunc, ps in [0,4)
      const int i1 = ip & 3;
      const float mu = ps - (float)ip;
      const float mu2 = mu * mu, mu3 = mu2 * mu;
      const float c0 = -0.5f * mu3 +        mu2 - 0.5f * mu;
      const float c1 =  1.5f * mu3 - 2.5f * mu2 + 1.0f;
      const float c2 = -1.5f * mu3 + 2.0f * mu2 + 0.5f * mu;
      const float c3 =  0.5f * mu3 - 0.5f * mu2;
      const int d0 = (0-i1)&3, d1 = (1-i1)&3, d2 = (2-i1)&3, d3 = (3-i1)&3;
      float4 cv;
      cv.x = d0==0 ? c1 : d0==1 ? c2 : d0==2 ? c3 : c0;
      cv.y = d1==0 ? c1 : d1==1 ? c2 : d1==2 ? c3 : c0;
      cv.z = d2==0 ? c1 : d2==1 ? c2 : d2==2 ? c3 : c0;
      cv.w = d3==0 ? c1 : d3==1 ? c2 : d3==2 ? c3 : c0;
      *reinterpret_cast<float4*>(coef + (size_t)b * 4) = cv;
    }
  }
}

// ---- GEMM: C'(8192 x 4096) = F . Wall^T. Round-0's proven 2-barrier
// single-buffer structure, re-partitioned for lower LDS-read traffic:
// block 256x128(g), 4 waves (2M x 2N), wave tile 128x64 (acc[8][4]).
// A and B each re-read only 2x from LDS -> 2.23e-5 B/FLOP (was 3.05e-5);
// LDS floor drops below the MFMA floor. 48 KB LDS, ~200 regs -> 2 blocks/CU.
#define BM 256
#define BN 128   // g-columns = 32 o's x 4 knots
#define BK 64

__global__ __launch_bounds__(256, 2) void gemm_kernel(
    const unsigned short* __restrict__ F,    // 8192x1024 bf16
    const unsigned short* __restrict__ Wb,   // 4096x1024 bf16, g-layout
    const float* __restrict__ coef,          // 8192x4 f32
    const float* __restrict__ bias,          // 4x1024 f32
    float* __restrict__ out)
{
  __shared__ unsigned short As[BM * BK];   // 32 KB
  __shared__ unsigned short Bs[BN * BK];   // 16 KB  (48 KB total)

  const int tid  = threadIdx.x;
  const int wave = tid >> 6;
  const int lane = tid & 63;
  const int row0  = blockIdx.y * BM;
  const int col0g = blockIdx.x * BN;       // g-row base of Wall

  // staging: thread t -> LDS slot t*16B; XOR chunk swizzle on global source
  const int srow = tid >> 3;               // 0..31
  const int scc  = tid & 7;
  const int sgc  = (scc ^ (srow & 7)) * 8; // r = srow + it*32 keeps r&7 == srow&7

  const int wr = (wave >> 1) * 128;        // 2 M-waves
  const int wc = (wave & 1) * 64;          // 2 N-waves
  const int fm = lane & 15;
  const int fq = lane >> 4;

  f32x4 acc[8][4];   // [mi][ni=knot] -> 128 AGPR
  const f32x4 zero = {0.f, 0.f, 0.f, 0.f};
  #pragma unroll
  for (int a = 0; a < 8; a++)
    #pragma unroll
    for (int b = 0; b < 4; b++)
      acc[a][b] = zero;

  const unsigned short* Abase = F  + (size_t)row0  * 1024;
  const unsigned short* Bbase = Wb + (size_t)col0g * 1024;

  for (int kb = 0; kb < 1024; kb += BK) {
    #pragma unroll
    for (int it = 0; it < 8; it++) {       // A: 256 rows
      const int r = srow + it * 32;
      __builtin_amdgcn_global_load_lds(
          (const __attribute__((address_space(1))) void*)(Abase + (size_t)r * 1024 + kb + sgc),
          (__attribute__((address_space(3))) void*)(As + r * BK + scc * 8), 16, 0, 0);
    }
    #pragma unroll
    for (int it = 0; it < 4; it++) {       // B: 128 rows
      const int r = srow + it * 32;
      __builtin_amdgcn_global_load_lds(
          (const __attribute__((address_space(1))) void*)(Bbase + (size_t)r * 1024 + kb + sgc),
          (__attribute__((address_space(3))) void*)(Bs + r * BK + scc * 8), 16, 0, 0);
    }
    __syncthreads();

    #pragma unroll
    for (int kk = 0; kk < BK; kk += 32) {
      bf16x8 af[8], bfr[4];
      #pragma unroll
      for (int mi = 0; mi < 8; mi++) {
        const int r  = wr + mi * 16 + fm;
        const int lc = ((kk >> 3) + fq) ^ (fm & 7);
        af[mi] = *reinterpret_cast<const bf16x8*>(As + r * BK + lc * 8);
      }
      #pragma unroll
      for (int ni = 0; ni < 4; ni++) {
        const int r  = wc + ni * 16 + fm;
        const int lc = ((kk >> 3) + fq) ^ (fm & 7);
        bfr[ni] = *reinterpret_cast<const bf16x8*>(Bs + r * BK + lc * 8);
      }
      #pragma unroll
      for (int mi = 0; mi < 8; mi++)
        #pragma unroll
        for (int ni = 0; ni < 4; ni++)
          acc[mi][ni] = __builtin_amdgcn_mfma_f32_16x16x32_bf16(
              af[mi], bfr[ni], acc[mi][ni], 0, 0, 0);
    }
    __syncthreads();
  }

  // ---- epilogue: v = sum_k c_k*(acc_k + bias_k[o]); fast elu; dense store
  const int o = fm + 16 * (2 * blockIdx.x + (wave & 1));   // this lane's output column
  const float b0 = bias[o];
  const float b1 = bias[OUT_DIM + o];
  const float b2 = bias[2 * OUT_DIM + o];
  const float b3 = bias[3 * OUT_DIM + o];
  #pragma unroll
  for (int mi = 0; mi < 8; mi++) {
    #pragma unroll
    for (int r = 0; r < 4; r++) {
      const int rloc = wr + mi * 16 + (fq << 2) + r;
      const float4 c = *reinterpret_cast<const float4*>(coef + (size_t)(row0 + rloc) * 4);
      float v = c.x * (acc[mi][0][r] + b0)
              + c.y * (acc[mi][1][r] + b1)
              + c.z * (acc[mi][2][r] + b2)
              + c.w * (acc[mi][3][r] + b3);
      // elu(alpha=1): exp(v)-1 via hw v_exp_f32; abs err ~1e-7 << 4.3e-3 threshold
      const float e = __expf(v) - 1.0f;
      v = (v > 0.0f) ? v : e;
      out[(size_t)(row0 + rloc) * OUT_DIM + o] = v;
    }
  }
}

extern "C" void kernel_launch(void* const* d_in, const int* in_sizes, int n_in,
                              void* d_out, int out_size, void* d_ws, size_t ws_size,
                              hipStream_t stream) {
  const float* x  = (const float*)d_in[0];   // (8192, 1025)
  const float* wk = (const float*)d_in[1];   // (4, 1024, 1024)
  const float* bk = (const float*)d_in[2];   // (4, 1024)
  float* out = (float*)d_out;                // (8192, 1024) fp32

  char* ws = (char*)d_ws;
  unsigned short* Wb = (unsigned short*)ws;                   // 8 MB
  unsigned short* F  = (unsigned short*)(ws + (8u << 20));    // 16 MB
  float* coef        = (float*)(ws + (24u << 20));            // 128 KB

  hipLaunchKernelGGL(prep_kernel, dim3(2048 + NROWS), dim3(256), 0, stream,
                     x, wk, Wb, F, coef);
  hipLaunchKernelGGL(gemm_kernel, dim3(4096 / BN, NROWS / BM), dim3(256), 0, stream,
                     F, Wb, coef, bk, out);
}